// Round 5
// baseline (1630.223 us; speedup 1.0000x reference)
//
#include <hip/hip_runtime.h>
#include <hip/hip_bf16.h>

#define TT 36
#define FF 18
#define HH 128
#define BB 16
#define BLOCK 256
#define SIGP 36   // Es row length (floats); 144 B rows, b128-aligned

typedef __attribute__((ext_vector_type(4))) float f32x4;
typedef __attribute__((ext_vector_type(8))) short bf16x8;

#define L2E  1.4426950408889634f
#define L2E2 2.8853900817779268f

static __device__ __forceinline__ unsigned short f2bf(float f) {
    unsigned int x = __builtin_bit_cast(unsigned int, f);
    unsigned int r = (x + 0x7fffu + ((x >> 16) & 1u)) >> 16;
    return (unsigned short)r;
}
#if __has_builtin(__builtin_amdgcn_rcpf)
static __device__ __forceinline__ float frcp(float x) { return __builtin_amdgcn_rcpf(x); }
#else
static __device__ __forceinline__ float frcp(float x) { return 1.f / x; }
#endif
#if __has_builtin(__builtin_amdgcn_exp2f)
static __device__ __forceinline__ float fexp2(float x) { return __builtin_amdgcn_exp2f(x); }
#else
static __device__ __forceinline__ float fexp2(float x) { return __expf(x * 0.69314718056f); }
#endif
static __device__ __forceinline__ f32x4 mfma16(bf16x8 a, bf16x8 b, f32x4 c) {
    return __builtin_amdgcn_mfma_f32_16x16x32_bf16(a, b, c, 0, 0, 0);
}

__global__ __launch_bounds__(BLOCK, 2) void enc_att_gru(
    const float* __restrict__ seqs, const float* __restrict__ mask,
    const float* __restrict__ Wh,   const float* __restrict__ bh,
    const float* __restrict__ Ws,   const float* __restrict__ bs,
    const float* __restrict__ Wo,   const float* __restrict__ bo,
    const float* __restrict__ W_ih, const float* __restrict__ W_hh,
    const float* __restrict__ b_ih, const float* __restrict__ b_hh,
    float* __restrict__ out)
{
    __shared__ __align__(16) float es_lds[BB * FF * SIGP];   // exp2(L2E2*sig), 41472 B
    __shared__ float Ws2_lds[TT * TT];                       // [tp][t], pre-scaled L2E2
    __shared__ float bs2_lds[TT];
    __shared__ __align__(16) float wo2_lds[TT];              // -2*wo
    __shared__ __align__(16) float el_lds[BB][SIGP];         // exp2(L2E2*lin_h)
    // fragment-major: element (bb, k) at chunk = (k>>3)*BB + bb, slot k&7
    __shared__ __align__(16) unsigned short h_lds[16 * BB][8]; // k: 0..127
    __shared__ __align__(16) unsigned short x_lds[4 * BB][8];  // k: 0..31 (F padded)
    __shared__ float mask_lds[BB][TT];

    const int tid  = threadIdx.x;
    const int wave = tid >> 6;
    const int lane = tid & 63;
    const int l15  = lane & 15;
    const int l4   = lane >> 4;
    const int bbase = blockIdx.x * BB;
    const int bb2a = tid >> 5;       // phase-B row A (0..7)
    const int bb2b = bb2a + 8;       // phase-B row B (8..15)
    const int f2  = tid & 31;        // phase-B feature (valid < 18)

    // ---- stage small tensors ----
    for (int idx = tid; idx < TT * TT; idx += BLOCK) {
        int t = idx / TT, tp = idx - t * TT;
        Ws2_lds[tp * TT + t] = L2E2 * Ws[idx];      // transposed + scaled
    }
    if (tid < TT) { bs2_lds[tid] = L2E2 * bs[tid]; wo2_lds[tid] = -2.f * Wo[tid]; }
    for (int idx = tid; idx < BB * TT; idx += BLOCK) {
        int bb = idx / TT, t = idx - bb * TT;
        mask_lds[bb][t] = mask[(size_t)(bbase + bb) * TT + t];
    }
    for (int idx = tid; idx < 16 * BB * 8; idx += BLOCK) ((unsigned short*)h_lds)[idx] = 0;
    for (int idx = tid; idx < 4 * BB * 8; idx += BLOCK) ((unsigned short*)x_lds)[idx] = 0;
    __syncthreads();

    // ---- precompute Es[bb][f][t] = exp2( L2E2*(bs[t] + sum_tp seq[bb][tp][f]*Ws[t][tp]) ) ----
    if (f2 < FF) {
#pragma unroll
        for (int half = 0; half < 2; ++half) {
            const int bb = half ? bb2b : bb2a;
            const size_t sb = (size_t)(bbase + bb) * (TT * FF) + f2;
            float* srow = &es_lds[(bb * FF + f2) * SIGP];
            for (int c = 0; c < 3; ++c) {              // t in chunks of 12
                float acc[12];
#pragma unroll
                for (int j = 0; j < 12; ++j) acc[j] = bs2_lds[c * 12 + j];
                for (int tp = 0; tp < TT; ++tp) {
                    float s = seqs[sb + (size_t)tp * FF];
#pragma unroll
                    for (int j = 0; j < 12; ++j)
                        acc[j] = fmaf(s, Ws2_lds[tp * TT + c * 12 + j], acc[j]);
                }
#pragma unroll
                for (int j = 0; j < 12; ++j) srow[c * 12 + j] = fexp2(acc[j]);
            }
        }
    }

    // ---- persistent weight fragments; wave owns units [wave*32, wave*32+32) ----
    // self-consistent k-map: k = kt*32 + l4*8 + j (cancels between A and B frags)
    bf16x8 whh[3][2][4];
#pragma unroll
    for (int g = 0; g < 3; ++g)
#pragma unroll
        for (int u = 0; u < 2; ++u)
#pragma unroll
            for (int kt = 0; kt < 4; ++kt) {
                const int o = g * HH + wave * 32 + u * 16 + l15;
                bf16x8 fr;
#pragma unroll
                for (int jj = 0; jj < 8; ++jj) {
                    int k = kt * 32 + l4 * 8 + jj;
                    fr[jj] = (short)f2bf(W_hh[(size_t)o * HH + k]);
                }
                whh[g][u][kt] = fr;
            }
    bf16x8 wih[3][2];
#pragma unroll
    for (int g = 0; g < 3; ++g)
#pragma unroll
        for (int u = 0; u < 2; ++u) {
            const int o = g * HH + wave * 32 + u * 16 + l15;
            bf16x8 fr;
#pragma unroll
            for (int jj = 0; jj < 8; ++jj) {
                int f = l4 * 8 + jj;
                fr[jj] = (f < FF) ? (short)f2bf(W_ih[(size_t)o * FF + f]) : (short)0;
            }
            wih[g][u] = fr;
        }
    const int tcol = 16 * wave + l15;    // lin_h output column (waves 0-2)
    bf16x8 whf[4];
#pragma unroll
    for (int kt = 0; kt < 4; ++kt) {
        bf16x8 fr;
#pragma unroll
        for (int jj = 0; jj < 8; ++jj) {
            int k = kt * 32 + l4 * 8 + jj;
            fr[jj] = (wave < 3 && tcol < TT) ? (short)f2bf(Wh[(size_t)tcol * HH + k]) : (short)0;
        }
        whf[kt] = fr;
    }
    float brz_r[2], brz_z[2], bn_i[2], bn_h[2];
#pragma unroll
    for (int u = 0; u < 2; ++u) {
        const int ju = wave * 32 + u * 16 + l15;
        brz_r[u] = b_ih[ju] + b_hh[ju];
        brz_z[u] = b_ih[HH + ju] + b_hh[HH + ju];
        bn_i[u]  = b_ih[2 * HH + ju];
        bn_h[u]  = b_hh[2 * HH + ju];
    }
    const float bh_reg = (wave < 3 && tcol < TT) ? bh[tcol] : 0.f;
    float c0 = bo[0];
    for (int tp = 0; tp < TT; ++tp) c0 += Wo[tp];

    float seq_curA = seqs[(size_t)(bbase + bb2a) * (TT * FF) + (f2 < FF ? f2 : FF - 1)];
    float seq_curB = seqs[(size_t)(bbase + bb2b) * (TT * FF) + (f2 < FF ? f2 : FF - 1)];

    float h_prev[2][4]  = {{0.f,0.f,0.f,0.f},{0.f,0.f,0.f,0.f}};
    float out_acc[2][4] = {{0.f,0.f,0.f,0.f},{0.f,0.f,0.f,0.f}};

    __syncthreads();

    for (int t = 0; t < TT; ++t) {
        // ---- Phase A: h A-frags (lane-linear) + lin_h->El + gh MFMAs ----
        bf16x8 ha[4];
#pragma unroll
        for (int kt = 0; kt < 4; ++kt)
            ha[kt] = *(const bf16x8*)(&h_lds[(kt * 4 + l4) * BB + l15][0]);
        if (wave < 3) {
            f32x4 a = {0.f, 0.f, 0.f, 0.f};
#pragma unroll
            for (int kt = 0; kt < 4; ++kt) a = mfma16(ha[kt], whf[kt], a);
            if (tcol < TT) {
#pragma unroll
                for (int r = 0; r < 4; ++r)
                    el_lds[l4 * 4 + r][tcol] = fexp2((a[r] + bh_reg) * L2E2);
            }
        }
        f32x4 acc_r[2], acc_z[2], acc_n[2];
#pragma unroll
        for (int u = 0; u < 2; ++u) {
            f32x4 zr = {0.f,0.f,0.f,0.f};
            acc_r[u] = zr; acc_z[u] = zr; acc_n[u] = zr;
#pragma unroll
            for (int kt = 0; kt < 4; ++kt) {
                acc_r[u] = mfma16(ha[kt], whh[0][u][kt], acc_r[u]);
                acc_z[u] = mfma16(ha[kt], whh[1][u][kt], acc_z[u]);
                acc_n[u] = mfma16(ha[kt], whh[2][u][kt], acc_n[u]);
            }
        }
        __syncthreads();   // el visible

        // ---- Phase B: e-scores for 2 rows/lane + in-register softmax + x ----
        {
            const int fs = (f2 < FF) ? f2 : (FF - 1);
            const float* srowA = &es_lds[(bb2a * FF + fs) * SIGP];
            const float* srowB = &es_lds[(bb2b * FF + fs) * SIGP];
            const float* lrowA = &el_lds[bb2a][0];
            const float* lrowB = &el_lds[bb2b][0];
            float a0 = c0, a1 = 0.f, a2 = 0.f, a3 = 0.f;
            float b0 = c0, b1 = 0.f, b2 = 0.f, b3 = 0.f;
#pragma unroll
            for (int g = 0; g < 9; ++g) {
                f32x4 svA = *(const f32x4*)(srowA + g * 4);
                f32x4 svB = *(const f32x4*)(srowB + g * 4);
                f32x4 lvA = *(const f32x4*)(lrowA + g * 4);
                f32x4 lvB = *(const f32x4*)(lrowB + g * 4);
                f32x4 wv  = *(const f32x4*)(&wo2_lds[g * 4]);
                a0 = fmaf(wv[0], frcp(fmaf(svA[0], lvA[0], 1.f)), a0);
                a1 = fmaf(wv[1], frcp(fmaf(svA[1], lvA[1], 1.f)), a1);
                a2 = fmaf(wv[2], frcp(fmaf(svA[2], lvA[2], 1.f)), a2);
                a3 = fmaf(wv[3], frcp(fmaf(svA[3], lvA[3], 1.f)), a3);
                b0 = fmaf(wv[0], frcp(fmaf(svB[0], lvB[0], 1.f)), b0);
                b1 = fmaf(wv[1], frcp(fmaf(svB[1], lvB[1], 1.f)), b1);
                b2 = fmaf(wv[2], frcp(fmaf(svB[2], lvB[2], 1.f)), b2);
                b3 = fmaf(wv[3], frcp(fmaf(svB[3], lvB[3], 1.f)), b3);
            }
            float eA = (a0 + a1) + (a2 + a3);
            float eB = (b0 + b1) + (b2 + b3);
            float mA = eA, mB = eB;
#pragma unroll
            for (int d = 1; d <= 16; d <<= 1) {
                mA = fmaxf(mA, __shfl_xor(mA, d));
                mB = fmaxf(mB, __shfl_xor(mB, d));
            }
            float pA = (f2 < FF) ? fexp2(L2E * (eA - mA)) : 0.f;
            float pB = (f2 < FF) ? fexp2(L2E * (eB - mB)) : 0.f;
            float sA = pA, sB = pB;
#pragma unroll
            for (int d = 1; d <= 16; d <<= 1) {
                sA += __shfl_xor(sA, d);
                sB += __shfl_xor(sB, d);
            }
            if (f2 < FF) {
                x_lds[(f2 >> 3) * BB + bb2a][f2 & 7] = f2bf(pA * frcp(sA) * seq_curA);
                x_lds[(f2 >> 3) * BB + bb2b][f2 & 7] = f2bf(pB * frcp(sB) * seq_curB);
                if (t + 1 < TT) {
                    seq_curA = seqs[(size_t)(bbase + bb2a) * (TT * FF) + (size_t)(t + 1) * FF + f2];
                    seq_curB = seqs[(size_t)(bbase + bb2b) * (TT * FF) + (size_t)(t + 1) * FF + f2];
                }
            }
        }
        __syncthreads();   // x visible

        // ---- Phase C: gi MFMAs + GRU elementwise (dense) + h store ----
        bf16x8 xa = *(const bf16x8*)(&x_lds[l4 * BB + l15][0]);
        f32x4 acc_gi[2];
#pragma unroll
        for (int u = 0; u < 2; ++u) {
            f32x4 zr = {0.f,0.f,0.f,0.f};
            acc_r[u] = mfma16(xa, wih[0][u], acc_r[u]);
            acc_z[u] = mfma16(xa, wih[1][u], acc_z[u]);
            acc_gi[u] = mfma16(xa, wih[2][u], zr);
        }
#pragma unroll
        for (int u = 0; u < 2; ++u) {
            const int ku = wave * 32 + u * 16 + l15;
            const int chunk = (ku >> 3);
#pragma unroll
            for (int r = 0; r < 4; ++r) {
                int bb = l4 * 4 + r;
                float rg = frcp(1.f + fexp2(-L2E * (acc_r[u][r] + brz_r[u])));
                float zg = frcp(1.f + fexp2(-L2E * (acc_z[u][r] + brz_z[u])));
                float gin = acc_gi[u][r] + bn_i[u] + rg * (acc_n[u][r] + bn_h[u]);
                float ng = 1.f - 2.f * frcp(1.f + fexp2(L2E2 * gin));
                float hn = fmaf(zg, h_prev[u][r] - ng, ng);
                h_prev[u][r] = hn;
                out_acc[u][r] = fmaf(hn, mask_lds[bb][t], out_acc[u][r]);
                h_lds[chunk * BB + bb][ku & 7] = f2bf(hn);
            }
        }
        __syncthreads();   // h ready for next step
    }

#pragma unroll
    for (int u = 0; u < 2; ++u) {
        const int ku = wave * 32 + u * 16 + l15;
#pragma unroll
        for (int r = 0; r < 4; ++r) {
            int bb = l4 * 4 + r;
            out[(size_t)(bbase + bb) * HH + ku] = out_acc[u][r];
        }
    }
}

extern "C" void kernel_launch(void* const* d_in, const int* in_sizes, int n_in,
                              void* d_out, int out_size, void* d_ws, size_t ws_size,
                              hipStream_t stream) {
    const float* seqs = (const float*)d_in[0];
    const float* mask = (const float*)d_in[1];
    const float* Wh   = (const float*)d_in[2];
    const float* bh   = (const float*)d_in[3];
    const float* Ws   = (const float*)d_in[4];
    const float* bs   = (const float*)d_in[5];
    const float* Wo   = (const float*)d_in[6];
    const float* bo   = (const float*)d_in[7];
    const float* W_ih = (const float*)d_in[8];
    const float* W_hh = (const float*)d_in[9];
    const float* b_ih = (const float*)d_in[10];
    const float* b_hh = (const float*)d_in[11];
    float* out = (float*)d_out;

    const int Btot = in_sizes[0] / (TT * FF);   // 16384
    const int grid = Btot / BB;                 // 1024
    enc_att_gru<<<grid, BLOCK, 0, stream>>>(seqs, mask, Wh, bh, Ws, bs, Wo, bo,
                                            W_ih, W_hh, b_ih, b_hh, out);
}

// Round 6
// 512.185 us; speedup vs baseline: 3.1829x; 3.1829x over previous
//
#include <hip/hip_runtime.h>
#include <hip/hip_bf16.h>

#define TT 36
#define FF 18
#define HH 128
#define BB 32
#define BLOCK 512
#define SIGP 36   // es/el row length (floats); 144 B rows, b128-aligned

typedef __attribute__((ext_vector_type(4))) float f32x4;
typedef __attribute__((ext_vector_type(8))) short bf16x8;

#define L2E  1.4426950408889634f
#define L2E2 2.8853900817779268f

static __device__ __forceinline__ unsigned short f2bf(float f) {
    unsigned int x = __builtin_bit_cast(unsigned int, f);
    unsigned int r = (x + 0x7fffu + ((x >> 16) & 1u)) >> 16;
    return (unsigned short)r;
}
#if __has_builtin(__builtin_amdgcn_rcpf)
static __device__ __forceinline__ float frcp(float x) { return __builtin_amdgcn_rcpf(x); }
#else
static __device__ __forceinline__ float frcp(float x) { return 1.f / x; }
#endif
#if __has_builtin(__builtin_amdgcn_exp2f)
static __device__ __forceinline__ float fexp2(float x) { return __builtin_amdgcn_exp2f(x); }
#else
static __device__ __forceinline__ float fexp2(float x) { return __expf(x * 0.69314718056f); }
#endif
static __device__ __forceinline__ f32x4 mfma16(bf16x8 a, bf16x8 b, f32x4 c) {
    return __builtin_amdgcn_mfma_f32_16x16x32_bf16(a, b, c, 0, 0, 0);
}

__global__ __launch_bounds__(BLOCK, 2) void enc_att_gru(
    const float* __restrict__ seqs, const float* __restrict__ mask,
    const float* __restrict__ Wh,   const float* __restrict__ bh,
    const float* __restrict__ Ws,   const float* __restrict__ bs,
    const float* __restrict__ Wo,   const float* __restrict__ bo,
    const float* __restrict__ W_ih, const float* __restrict__ W_hh,
    const float* __restrict__ b_ih, const float* __restrict__ b_hh,
    float* __restrict__ out)
{
    __shared__ __align__(16) float es_lds[BB * FF * SIGP];   // Es = exp2(L2E2*sig), 82944 B
    __shared__ float Ws2_lds[TT * TT];                       // [tp][t], pre-scaled L2E2
    __shared__ float bs2_lds[TT];
    __shared__ __align__(16) float wo2_lds[TT];              // -2*wo
    __shared__ __align__(16) float el_lds[BB][SIGP];         // El = exp2(L2E2*lin_h)
    // fragment-major: element (bb, k) at chunk = (k>>3)*BB + bb, slot k&7
    __shared__ __align__(16) unsigned short h_lds[16 * BB][8]; // k: 0..127
    __shared__ __align__(16) unsigned short x_lds[4 * BB][8];  // k: 0..31 (F padded)
    __shared__ float mask_lds[BB][TT];

    const int tid  = threadIdx.x;
    const int wave = tid >> 6;
    const int lane = tid & 63;
    const int l15  = lane & 15;
    const int l4   = lane >> 4;
    const int bbase = blockIdx.x * BB;
    const int bb2a = tid >> 5;       // phase-B row A (0..15)
    const int bb2b = bb2a + 16;      // phase-B row B (16..31)
    const int f2  = tid & 31;        // phase-B feature (valid < 18)

    // ---- stage small tensors ----
    for (int idx = tid; idx < TT * TT; idx += BLOCK) {
        int t = idx / TT, tp = idx - t * TT;
        Ws2_lds[tp * TT + t] = L2E2 * Ws[idx];      // transposed + scaled
    }
    if (tid < TT) { bs2_lds[tid] = L2E2 * bs[tid]; wo2_lds[tid] = -2.f * Wo[tid]; }
    for (int idx = tid; idx < BB * TT; idx += BLOCK) {
        int bb = idx / TT, t = idx - bb * TT;
        mask_lds[bb][t] = mask[(size_t)(bbase + bb) * TT + t];
    }
    for (int idx = tid; idx < 16 * BB * 8; idx += BLOCK) ((unsigned short*)h_lds)[idx] = 0;
    for (int idx = tid; idx < 4 * BB * 8; idx += BLOCK) ((unsigned short*)x_lds)[idx] = 0;
    __syncthreads();

    // ---- precompute Es[bb][f][t] = exp2( L2E2*(bs[t] + sum_tp seq[bb][tp][f]*Ws[t][tp]) ) ----
    for (int task = tid; task < BB * FF; task += BLOCK) {
        const int bb = task / FF;
        const int f  = task - bb * FF;
        const size_t sb = (size_t)(bbase + bb) * (TT * FF) + f;
        float* srow = &es_lds[task * SIGP];
        for (int c = 0; c < 3; ++c) {              // t in chunks of 12
            float acc[12];
#pragma unroll
            for (int j = 0; j < 12; ++j) acc[j] = bs2_lds[c * 12 + j];
            for (int tp = 0; tp < TT; ++tp) {
                float s = seqs[sb + (size_t)tp * FF];
#pragma unroll
                for (int j = 0; j < 12; ++j)
                    acc[j] = fmaf(s, Ws2_lds[tp * TT + c * 12 + j], acc[j]);
            }
#pragma unroll
            for (int j = 0; j < 12; ++j) srow[c * 12 + j] = fexp2(acc[j]);
        }
    }

    // ---- persistent weight fragments; wave owns units [wave*16, wave*16+16) ----
    // self-consistent k-map: k = kt*32 + l4*8 + j (cancels between A and B frags)
    bf16x8 whh[3][4];
#pragma unroll
    for (int g = 0; g < 3; ++g)
#pragma unroll
        for (int kt = 0; kt < 4; ++kt) {
            const int o = g * HH + wave * 16 + l15;
            bf16x8 fr;
#pragma unroll
            for (int jj = 0; jj < 8; ++jj) {
                int k = kt * 32 + l4 * 8 + jj;
                fr[jj] = (short)f2bf(W_hh[(size_t)o * HH + k]);
            }
            whh[g][kt] = fr;
        }
    bf16x8 wih[3];
#pragma unroll
    for (int g = 0; g < 3; ++g) {
        const int o = g * HH + wave * 16 + l15;
        bf16x8 fr;
#pragma unroll
        for (int jj = 0; jj < 8; ++jj) {
            int f = l4 * 8 + jj;
            fr[jj] = (f < FF) ? (short)f2bf(W_ih[(size_t)o * FF + f]) : (short)0;
        }
        wih[g] = fr;
    }
    // lin_h duty: waves 0-2 -> row-tile 0, waves 4-6 -> row-tile 1
    const int wgrp = (wave < 4) ? wave : (wave - 4);
    const bool linh_wave = (wgrp < 3);
    const int lrt  = (wave < 4) ? 0 : 1;        // lin_h row-tile
    const int tcol = wgrp * 16 + l15;           // lin_h output column (t)
    bf16x8 whf[4];
#pragma unroll
    for (int kt = 0; kt < 4; ++kt) {
        bf16x8 fr;
#pragma unroll
        for (int jj = 0; jj < 8; ++jj) {
            int k = kt * 32 + l4 * 8 + jj;
            fr[jj] = (linh_wave && tcol < TT) ? (short)f2bf(Wh[(size_t)tcol * HH + k]) : (short)0;
        }
        whf[kt] = fr;
    }
    const int junit = wave * 16 + l15;   // GRU unit this lane owns
    const float brz_r = b_ih[junit] + b_hh[junit];
    const float brz_z = b_ih[HH + junit] + b_hh[HH + junit];
    const float bn_i  = b_ih[2 * HH + junit];
    const float bn_h  = b_hh[2 * HH + junit];
    const float bh_reg = (linh_wave && tcol < TT) ? bh[tcol] : 0.f;
    float c0 = bo[0];
    for (int tp = 0; tp < TT; ++tp) c0 += Wo[tp];

    const int fsafe = (f2 < FF) ? f2 : (FF - 1);
    float seq_curA = seqs[(size_t)(bbase + bb2a) * (TT * FF) + fsafe];
    float seq_curB = seqs[(size_t)(bbase + bb2b) * (TT * FF) + fsafe];

    float h_prev[2][4]  = {{0.f,0.f,0.f,0.f},{0.f,0.f,0.f,0.f}};
    float out_acc[2][4] = {{0.f,0.f,0.f,0.f},{0.f,0.f,0.f,0.f}};

    __syncthreads();

    for (int t = 0; t < TT; ++t) {
        // ---- Phase A: lin_h MFMA -> El (6 waves; waves 3,7 pass through) ----
        if (linh_wave) {
            bf16x8 ha0[4];
#pragma unroll
            for (int kt = 0; kt < 4; ++kt)
                ha0[kt] = *(const bf16x8*)(&h_lds[(kt * 4 + l4) * BB + lrt * 16 + l15][0]);
            f32x4 a = {0.f, 0.f, 0.f, 0.f};
#pragma unroll
            for (int kt = 0; kt < 4; ++kt) a = mfma16(ha0[kt], whf[kt], a);
            if (tcol < TT) {
#pragma unroll
                for (int r = 0; r < 4; ++r)
                    el_lds[lrt * 16 + l4 * 4 + r][tcol] = fexp2((a[r] + bh_reg) * L2E2);
            }
        }
        __syncthreads();   // el visible

        // ---- Phase B: e-scores for 2 rows/lane (no max pass; e bounded) + softmax + x ----
        {
            const float* srowA = &es_lds[(bb2a * FF + fsafe) * SIGP];
            const float* srowB = &es_lds[(bb2b * FF + fsafe) * SIGP];
            const float* lrowA = &el_lds[bb2a][0];
            const float* lrowB = &el_lds[bb2b][0];
            float a0 = c0, a1 = 0.f, a2 = 0.f, a3 = 0.f;
            float b0 = c0, b1 = 0.f, b2 = 0.f, b3 = 0.f;
#pragma unroll
            for (int g = 0; g < 9; ++g) {
                f32x4 svA = *(const f32x4*)(srowA + g * 4);
                f32x4 lvA = *(const f32x4*)(lrowA + g * 4);
                f32x4 svB = *(const f32x4*)(srowB + g * 4);
                f32x4 lvB = *(const f32x4*)(lrowB + g * 4);
                f32x4 wv  = *(const f32x4*)(&wo2_lds[g * 4]);
                a0 = fmaf(wv[0], frcp(fmaf(svA[0], lvA[0], 1.f)), a0);
                a1 = fmaf(wv[1], frcp(fmaf(svA[1], lvA[1], 1.f)), a1);
                a2 = fmaf(wv[2], frcp(fmaf(svA[2], lvA[2], 1.f)), a2);
                a3 = fmaf(wv[3], frcp(fmaf(svA[3], lvA[3], 1.f)), a3);
                b0 = fmaf(wv[0], frcp(fmaf(svB[0], lvB[0], 1.f)), b0);
                b1 = fmaf(wv[1], frcp(fmaf(svB[1], lvB[1], 1.f)), b1);
                b2 = fmaf(wv[2], frcp(fmaf(svB[2], lvB[2], 1.f)), b2);
                b3 = fmaf(wv[3], frcp(fmaf(svB[3], lvB[3], 1.f)), b3);
            }
            float eA = (a0 + a1) + (a2 + a3);
            float eB = (b0 + b1) + (b2 + b3);
            // |e| <= |bo| + sum|wo| ~ 1.5 -> exp never overflows; skip max subtraction
            float pA = (f2 < FF) ? fexp2(L2E * eA) : 0.f;
            float pB = (f2 < FF) ? fexp2(L2E * eB) : 0.f;
            float sA = pA, sB = pB;
#pragma unroll
            for (int d = 1; d <= 16; d <<= 1) {
                sA += __shfl_xor(sA, d);
                sB += __shfl_xor(sB, d);
            }
            if (f2 < FF) {
                x_lds[(f2 >> 3) * BB + bb2a][f2 & 7] = f2bf(pA * frcp(sA) * seq_curA);
                x_lds[(f2 >> 3) * BB + bb2b][f2 & 7] = f2bf(pB * frcp(sB) * seq_curB);
                if (t + 1 < TT) {
                    seq_curA = seqs[(size_t)(bbase + bb2a) * (TT * FF) + (size_t)(t + 1) * FF + f2];
                    seq_curB = seqs[(size_t)(bbase + bb2b) * (TT * FF) + (size_t)(t + 1) * FF + f2];
                }
            }
        }
        __syncthreads();   // x visible

        // ---- Phase C: per row-tile, gh+gi MFMAs + GRU elementwise + h store ----
#pragma unroll
        for (int rt = 0; rt < 2; ++rt) {
            bf16x8 ha[4];
#pragma unroll
            for (int kt = 0; kt < 4; ++kt)
                ha[kt] = *(const bf16x8*)(&h_lds[(kt * 4 + l4) * BB + rt * 16 + l15][0]);
            f32x4 ar = {0.f,0.f,0.f,0.f}, az = {0.f,0.f,0.f,0.f}, an = {0.f,0.f,0.f,0.f};
#pragma unroll
            for (int kt = 0; kt < 4; ++kt) {
                ar = mfma16(ha[kt], whh[0][kt], ar);
                az = mfma16(ha[kt], whh[1][kt], az);
                an = mfma16(ha[kt], whh[2][kt], an);
            }
            bf16x8 xa = *(const bf16x8*)(&x_lds[l4 * BB + rt * 16 + l15][0]);
            ar = mfma16(xa, wih[0], ar);
            az = mfma16(xa, wih[1], az);
            f32x4 zero4 = {0.f, 0.f, 0.f, 0.f};
            f32x4 agi = mfma16(xa, wih[2], zero4);
#pragma unroll
            for (int r = 0; r < 4; ++r) {
                int bb = rt * 16 + l4 * 4 + r;
                float rg = frcp(1.f + fexp2(-L2E * (ar[r] + brz_r)));
                float zg = frcp(1.f + fexp2(-L2E * (az[r] + brz_z)));
                float gin = agi[r] + bn_i + rg * (an[r] + bn_h);
                float ng = 1.f - 2.f * frcp(1.f + fexp2(L2E2 * gin));
                float hn = fmaf(zg, h_prev[rt][r] - ng, ng);
                h_prev[rt][r] = hn;
                out_acc[rt][r] = fmaf(hn, mask_lds[bb][t], out_acc[rt][r]);
                h_lds[(junit >> 3) * BB + bb][junit & 7] = f2bf(hn);
            }
        }
        __syncthreads();   // h ready for next step
    }

#pragma unroll
    for (int rt = 0; rt < 2; ++rt)
#pragma unroll
        for (int r = 0; r < 4; ++r) {
            int bb = rt * 16 + l4 * 4 + r;
            out[(size_t)(bbase + bb) * HH + junit] = out_acc[rt][r];
        }
}

extern "C" void kernel_launch(void* const* d_in, const int* in_sizes, int n_in,
                              void* d_out, int out_size, void* d_ws, size_t ws_size,
                              hipStream_t stream) {
    const float* seqs = (const float*)d_in[0];
    const float* mask = (const float*)d_in[1];
    const float* Wh   = (const float*)d_in[2];
    const float* bh   = (const float*)d_in[3];
    const float* Ws   = (const float*)d_in[4];
    const float* bs   = (const float*)d_in[5];
    const float* Wo   = (const float*)d_in[6];
    const float* bo   = (const float*)d_in[7];
    const float* W_ih = (const float*)d_in[8];
    const float* W_hh = (const float*)d_in[9];
    const float* b_ih = (const float*)d_in[10];
    const float* b_hh = (const float*)d_in[11];
    float* out = (float*)d_out;

    const int Btot = in_sizes[0] / (TT * FF);   // 16384
    const int grid = Btot / BB;                 // 512
    enc_att_gru<<<grid, BLOCK, 0, stream>>>(seqs, mask, Wh, bh, Ws, bs, Wo, bo,
                                            W_ih, W_hh, b_ih, b_hh, out);
}

// Round 7
// 313.804 us; speedup vs baseline: 5.1950x; 1.6322x over previous
//
#include <hip/hip_runtime.h>
#include <hip/hip_bf16.h>

#define TT 36
#define FF 18
#define HH 128
#define BB 16
#define BLOCK 512
#define SIGP 36   // es/el row length (floats); 144 B rows, b128-aligned

typedef __attribute__((ext_vector_type(4))) float f32x4;
typedef __attribute__((ext_vector_type(8))) short bf16x8;

#define L2E  1.4426950408889634f
#define L2E2 2.8853900817779268f

static __device__ __forceinline__ unsigned short f2bf(float f) {
    unsigned int x = __builtin_bit_cast(unsigned int, f);
    unsigned int r = (x + 0x7fffu + ((x >> 16) & 1u)) >> 16;
    return (unsigned short)r;
}
#if __has_builtin(__builtin_amdgcn_rcpf)
static __device__ __forceinline__ float frcp(float x) { return __builtin_amdgcn_rcpf(x); }
#else
static __device__ __forceinline__ float frcp(float x) { return 1.f / x; }
#endif
#if __has_builtin(__builtin_amdgcn_exp2f)
static __device__ __forceinline__ float fexp2(float x) { return __builtin_amdgcn_exp2f(x); }
#else
static __device__ __forceinline__ float fexp2(float x) { return __expf(x * 0.69314718056f); }
#endif
static __device__ __forceinline__ f32x4 mfma16(bf16x8 a, bf16x8 b, f32x4 c) {
    return __builtin_amdgcn_mfma_f32_16x16x32_bf16(a, b, c, 0, 0, 0);
}
// XOR chunk swizzle: 16B chunk (c, bb) lives at slot bb^c of chunk-row c.
// Spreads the l4-groups of the phase-C b16 writes across banks; b128 reads stay optimal.
static __device__ __forceinline__ unsigned hxoff(int c, int bb) {
    return (unsigned)((c * BB + (bb ^ c)) << 4);
}

__global__ __launch_bounds__(BLOCK, 2) void enc_att_gru(
    const float* __restrict__ seqs, const float* __restrict__ mask,
    const float* __restrict__ Wh,   const float* __restrict__ bh,
    const float* __restrict__ Ws,   const float* __restrict__ bs,
    const float* __restrict__ Wo,   const float* __restrict__ bo,
    const float* __restrict__ W_ih, const float* __restrict__ W_hh,
    const float* __restrict__ b_ih, const float* __restrict__ b_hh,
    float* __restrict__ out)
{
    __shared__ __align__(16) float es_lds[BB * FF * SIGP];   // Es = exp2(L2E2*sig), 41472 B
    __shared__ float Ws2_lds[TT * TT];                       // [tp][t], pre-scaled L2E2
    __shared__ float bs2_lds[TT];
    __shared__ __align__(16) float wo2_lds[TT];              // -2*wo
    __shared__ __align__(16) float el_lds[BB][SIGP];         // El = exp2(L2E2*lin_h)
    __shared__ __align__(16) unsigned short h_lds[16 * BB * 8]; // swizzled chunks, k: 0..127
    __shared__ __align__(16) unsigned short x_lds[4 * BB * 8];  // swizzled chunks, k: 0..31
    __shared__ float mask_lds[BB][TT];

    const int tid  = threadIdx.x;
    const int wave = tid >> 6;
    const int lane = tid & 63;
    const int l15  = lane & 15;
    const int l4   = lane >> 4;
    const int bbase = blockIdx.x * BB;
    const int bb2 = tid >> 5;      // phase-B batch row (0..15)
    const int f2  = tid & 31;      // phase-B feature (valid < 18)

    // ---- stage small tensors ----
    for (int idx = tid; idx < TT * TT; idx += BLOCK) {
        int t = idx / TT, tp = idx - t * TT;
        Ws2_lds[tp * TT + t] = L2E2 * Ws[idx];      // transposed + scaled
    }
    if (tid < TT) { bs2_lds[tid] = L2E2 * bs[tid]; wo2_lds[tid] = -2.f * Wo[tid]; }
    for (int idx = tid; idx < BB * TT; idx += BLOCK) {
        int bb = idx / TT, t = idx - bb * TT;
        mask_lds[bb][t] = mask[(size_t)(bbase + bb) * TT + t];
    }
    for (int idx = tid; idx < 16 * BB * 8; idx += BLOCK) h_lds[idx] = 0;
    for (int idx = tid; idx < 4 * BB * 8; idx += BLOCK) x_lds[idx] = 0;
    __syncthreads();

    // ---- precompute Es[bb][f][t] = exp2( L2E2*(bs[t] + sum_tp seq[bb][tp][f]*Ws[t][tp]) ) ----
    if (f2 < FF) {
        const size_t sb = (size_t)(bbase + bb2) * (TT * FF) + f2;
        float* srow = &es_lds[(bb2 * FF + f2) * SIGP];
        for (int c = 0; c < 3; ++c) {              // t in chunks of 12
            float acc[12];
#pragma unroll
            for (int j = 0; j < 12; ++j) acc[j] = bs2_lds[c * 12 + j];
            for (int tp = 0; tp < TT; ++tp) {
                float s = seqs[sb + (size_t)tp * FF];
#pragma unroll
                for (int j = 0; j < 12; ++j)
                    acc[j] = fmaf(s, Ws2_lds[tp * TT + c * 12 + j], acc[j]);
            }
#pragma unroll
            for (int j = 0; j < 12; ++j) srow[c * 12 + j] = fexp2(acc[j]);
        }
    }

    // ---- persistent weight fragments (self-consistent k-map: k = kt*32 + l4*8 + j) ----
    bf16x8 whh[3][4];
    for (int g = 0; g < 3; ++g)
        for (int kt = 0; kt < 4; ++kt) {
            const int o = g * HH + 16 * wave + l15;
            bf16x8 fr;
#pragma unroll
            for (int jj = 0; jj < 8; ++jj) {
                int k = kt * 32 + l4 * 8 + jj;
                fr[jj] = (short)f2bf(W_hh[(size_t)o * HH + k]);
            }
            whh[g][kt] = fr;
        }
    bf16x8 wih[3];
    for (int g = 0; g < 3; ++g) {
        const int o = g * HH + 16 * wave + l15;
        bf16x8 fr;
#pragma unroll
        for (int jj = 0; jj < 8; ++jj) {
            int f = l4 * 8 + jj;
            fr[jj] = (f < FF) ? (short)f2bf(W_ih[(size_t)o * FF + f]) : (short)0;
        }
        wih[g] = fr;
    }
    const int tcol = 16 * wave + l15;
    bf16x8 whf[4];
    for (int kt = 0; kt < 4; ++kt) {
        bf16x8 fr;
#pragma unroll
        for (int jj = 0; jj < 8; ++jj) {
            int k = kt * 32 + l4 * 8 + jj;
            fr[jj] = (wave < 3 && tcol < TT) ? (short)f2bf(Wh[(size_t)tcol * HH + k]) : (short)0;
        }
        whf[kt] = fr;
    }
    const int junit = 16 * wave + l15;
    const float brz_r = b_ih[junit] + b_hh[junit];
    const float brz_z = b_ih[HH + junit] + b_hh[HH + junit];
    const float bn_i  = b_ih[2 * HH + junit];
    const float bn_h  = b_hh[2 * HH + junit];
    const float bh_reg = (wave < 3 && tcol < TT) ? bh[tcol] : 0.f;
    float c0 = bo[0];
    for (int tp = 0; tp < TT; ++tp) c0 += Wo[tp];   // e = c0 + sum wo2[t]*rcp(1+Es*El)

    const int fsafe = (f2 < FF) ? f2 : (FF - 1);
    float seq_cur = seqs[(size_t)(bbase + bb2) * (TT * FF) + fsafe];

    float h_prev[4]  = {0.f, 0.f, 0.f, 0.f};
    float out_acc[4] = {0.f, 0.f, 0.f, 0.f};

    __syncthreads();

    for (int t = 0; t < TT; ++t) {
        // ---- Phase A: h A-frags (swizzled chunks) + lin_h -> El + gh MFMAs ----
        bf16x8 ha[4];
#pragma unroll
        for (int kt = 0; kt < 4; ++kt)
            ha[kt] = *(const bf16x8*)((const char*)h_lds + hxoff(kt * 4 + l4, l15));
        if (wave < 3) {
            f32x4 a = {0.f, 0.f, 0.f, 0.f};
#pragma unroll
            for (int kt = 0; kt < 4; ++kt) a = mfma16(ha[kt], whf[kt], a);
            if (tcol < TT) {
#pragma unroll
                for (int r = 0; r < 4; ++r)
                    el_lds[l4 * 4 + r][tcol] = fexp2((a[r] + bh_reg) * L2E2);
            }
        }
        f32x4 acc_r = {0.f,0.f,0.f,0.f}, acc_z = {0.f,0.f,0.f,0.f}, acc_n = {0.f,0.f,0.f,0.f};
#pragma unroll
        for (int kt = 0; kt < 4; ++kt) {
            acc_r = mfma16(ha[kt], whh[0][kt], acc_r);
            acc_z = mfma16(ha[kt], whh[1][kt], acc_z);
            acc_n = mfma16(ha[kt], whh[2][kt], acc_n);
        }
        __syncthreads();   // el visible

        // ---- Phase B: e-scores (Es*El form, 1 trans/elem) + no-max softmax + x ----
        {
            const float* srow = &es_lds[(bb2 * FF + fsafe) * SIGP];
            const float* lrow = &el_lds[bb2][0];
            float a0 = c0, a1 = 0.f, a2 = 0.f, a3 = 0.f;
#pragma unroll
            for (int g = 0; g < 9; ++g) {
                f32x4 sv = *(const f32x4*)(srow + g * 4);
                f32x4 lv = *(const f32x4*)(lrow + g * 4);
                f32x4 wv = *(const f32x4*)(&wo2_lds[g * 4]);
                a0 = fmaf(wv[0], frcp(fmaf(sv[0], lv[0], 1.f)), a0);
                a1 = fmaf(wv[1], frcp(fmaf(sv[1], lv[1], 1.f)), a1);
                a2 = fmaf(wv[2], frcp(fmaf(sv[2], lv[2], 1.f)), a2);
                a3 = fmaf(wv[3], frcp(fmaf(sv[3], lv[3], 1.f)), a3);
            }
            float eacc = (a0 + a1) + (a2 + a3);
            // |e| <= |bo| + sum|wo| ~ 1.5 -> exp2 can't overflow; skip max pass
            float p = (f2 < FF) ? fexp2(L2E * eacc) : 0.f;
            float s = p;
#pragma unroll
            for (int d = 1; d <= 16; d <<= 1) s += __shfl_xor(s, d);
            if (f2 < FF) {
                *(unsigned short*)((char*)x_lds + hxoff(f2 >> 3, bb2) + (f2 & 7) * 2)
                    = f2bf(p * frcp(s) * seq_cur);
                if (t + 1 < TT)
                    seq_cur = seqs[(size_t)(bbase + bb2) * (TT * FF) + (size_t)(t + 1) * FF + f2];
            }
        }
        __syncthreads();   // x visible

        // ---- Phase C: gi MFMA + GRU elementwise + h store (swizzled) ----
        bf16x8 xa = *(const bf16x8*)((const char*)x_lds + hxoff(l4, l15));
        acc_r = mfma16(xa, wih[0], acc_r);
        acc_z = mfma16(xa, wih[1], acc_z);
        f32x4 zero4 = {0.f, 0.f, 0.f, 0.f};
        f32x4 acc_gi = mfma16(xa, wih[2], zero4);
#pragma unroll
        for (int r = 0; r < 4; ++r) {
            int bb = l4 * 4 + r;
            float rg = frcp(1.f + fexp2(-L2E * (acc_r[r] + brz_r)));
            float zg = frcp(1.f + fexp2(-L2E * (acc_z[r] + brz_z)));
            float gin = acc_gi[r] + bn_i + rg * (acc_n[r] + bn_h);
            float ng = 1.f - 2.f * frcp(1.f + fexp2(L2E2 * gin));
            float hn = fmaf(zg, h_prev[r] - ng, ng);
            h_prev[r] = hn;
            out_acc[r] = fmaf(hn, mask_lds[bb][t], out_acc[r]);
            *(unsigned short*)((char*)h_lds + hxoff(junit >> 3, bb) + (junit & 7) * 2) = f2bf(hn);
        }
        __syncthreads();   // h ready for next step
    }

#pragma unroll
    for (int r = 0; r < 4; ++r) {
        int bb = l4 * 4 + r;
        out[(size_t)(bbase + bb) * HH + junit] = out_acc[r];
    }
}

extern "C" void kernel_launch(void* const* d_in, const int* in_sizes, int n_in,
                              void* d_out, int out_size, void* d_ws, size_t ws_size,
                              hipStream_t stream) {
    const float* seqs = (const float*)d_in[0];
    const float* mask = (const float*)d_in[1];
    const float* Wh   = (const float*)d_in[2];
    const float* bh   = (const float*)d_in[3];
    const float* Ws   = (const float*)d_in[4];
    const float* bs   = (const float*)d_in[5];
    const float* Wo   = (const float*)d_in[6];
    const float* bo   = (const float*)d_in[7];
    const float* W_ih = (const float*)d_in[8];
    const float* W_hh = (const float*)d_in[9];
    const float* b_ih = (const float*)d_in[10];
    const float* b_hh = (const float*)d_in[11];
    float* out = (float*)d_out;

    const int Btot = in_sizes[0] / (TT * FF);   // 16384
    const int grid = Btot / BB;                 // 1024
    enc_att_gru<<<grid, BLOCK, 0, stream>>>(seqs, mask, Wh, bh, Ws, bs, Wo, bo,
                                            W_ih, W_hh, b_ih, b_hh, out);
}